// Round 8
// baseline (340.225 us; speedup 1.0000x reference)
//
#include <hip/hip_runtime.h>
#include <hip/hip_bf16.h>
#include <math.h>

// Problem constants
#define EMBED 512
#define NHEAD 8
#define HDIM 64
#define FFN 2048
#define BB 4
#define SS 2048
#define MROWS (BB*SS)   // 8192
#define NB ((size_t)MROWS * EMBED)   // 4M elems = 2^22
#define LN_EPS 1e-5f
#define QSCALE 0.180336880111f   // 0.125 * log2(e)

typedef __attribute__((ext_vector_type(8))) short short8;
typedef __attribute__((ext_vector_type(4))) float floatx4;

__device__ inline float bf2f(__hip_bfloat16 x) { return __bfloat162float(x); }
__device__ inline __hip_bfloat16 f2bf(float x) { return __float2bfloat16(x); }

__device__ inline float gelu_f(float x) {
    return 0.5f * x * (1.0f + erff(x * 0.70710678118654752f));
}

__device__ inline void async_copy16(const void* g, void* l) {
    __builtin_amdgcn_global_load_lds(
        (const __attribute__((address_space(1))) void*)g,
        (__attribute__((address_space(3))) void*)l, 16, 0, 0);
}

__device__ inline int sane_f(float v) {
    return (v == v) && (fabsf(v) > 0x1p-40f) && (fabsf(v) < 0x1p40f);
}

// ---------------- fused prep: qkv cvt + all weight transposes + bias cvt + dtype detect ----------------
__global__ __launch_bounds__(256) void prep_kernel(
    const void* __restrict__ query, const void* __restrict__ keyi, const void* __restrict__ vali,
    const void* __restrict__ Wq, const void* __restrict__ Wk, const void* __restrict__ Wv,
    const void* __restrict__ Wo, const void* __restrict__ W1, const void* __restrict__ W2,
    const void* __restrict__ bq, const void* __restrict__ bk, const void* __restrict__ bv,
    const void* __restrict__ bo, const void* __restrict__ b1, const void* __restrict__ b2,
    const void* __restrict__ g1, const void* __restrict__ be1,
    const void* __restrict__ g2, const void* __restrict__ be2,
    __hip_bfloat16* __restrict__ qkvbf,
    __hip_bfloat16* __restrict__ Wcat,     // WqT|WkT|WvT|WoT|W1T|W2T
    __hip_bfloat16* __restrict__ biasb,
    int* __restrict__ dflag)
{
    __shared__ __hip_bfloat16 L[64][65];
    const int f32 = sane_f(((const float*)query)[7]) + sane_f(((const float*)query)[1031]) +
                    sane_f(((const float*)query)[200003]) + sane_f(((const float*)query)[1000003]) >= 3;
    const int t = threadIdx.x;
    const int blk = blockIdx.x;

    if (blk < 6144) {   // qkv convert, 8 elems/thread
        size_t pos = ((size_t)blk * 256 + t) * 8;
        int sel = (int)(pos >> 22);
        size_t off = pos & (NB - 1);
        const void* src = sel == 0 ? query : sel == 1 ? keyi : vali;
        if (f32) {
            const float* s = (const float*)src + off;
            float4 f0 = *reinterpret_cast<const float4*>(s);
            float4 f1 = *reinterpret_cast<const float4*>(s + 4);
            alignas(16) __hip_bfloat16 h[8] = {
                f2bf(f0.x), f2bf(f0.y), f2bf(f0.z), f2bf(f0.w),
                f2bf(f1.x), f2bf(f1.y), f2bf(f1.z), f2bf(f1.w)};
            *reinterpret_cast<uint4*>(qkvbf + pos) = *reinterpret_cast<const uint4*>(h);
        } else {
            *reinterpret_cast<uint4*>(qkvbf + pos) =
                *reinterpret_cast<const uint4*>((const __hip_bfloat16*)src + off);
        }
        return;
    }

    const void* src; __hip_bfloat16* dst; int R, C, r0, c0;
    if (blk < 6400) {          // W1 [512][2048] -> W1T
        int b2i = blk - 6144; src = W1; dst = Wcat + 4 * 512 * 512;
        R = 512; C = 2048; r0 = (b2i >> 5) * 64; c0 = (b2i & 31) * 64;
    } else if (blk < 6656) {   // W2 [2048][512] -> W2T
        int b3 = blk - 6400; src = W2; dst = Wcat + 4 * 512 * 512 + 512 * 2048;
        R = 2048; C = 512; r0 = (b3 >> 3) * 64; c0 = (b3 & 7) * 64;
    } else if (blk < 6912) {   // Wq/Wk/Wv/Wo 512x512
        int b4 = blk - 6656; int which = b4 >> 6; int tile = b4 & 63;
        src = which == 0 ? Wq : which == 1 ? Wk : which == 2 ? Wv : Wo;
        dst = Wcat + (size_t)which * 512 * 512;
        R = 512; C = 512; r0 = (tile >> 3) * 64; c0 = (tile & 7) * 64;
    } else {                   // biases / ln params / dtype flag
        if (t == 0) *dflag = f32 ? 1 : 0;
        const void* srcs[10] = {bq, bk, bv, bo, b1, b2, g1, be1, g2, be2};
        const int offs[10] = {0, 512, 1024, 1536, 2048, 4096, 4608, 5120, 5632, 6144};
        const int lens[10] = {512, 512, 512, 512, 2048, 512, 512, 512, 512, 512};
        for (int a = 0; a < 10; ++a)
            for (int i = t; i < lens[a]; i += 256)
                biasb[offs[a] + i] = f32 ? f2bf(((const float*)srcs[a])[i])
                                         : ((const __hip_bfloat16*)srcs[a])[i];
        return;
    }
    for (int c = t; c < 4096; c += 256) {
        int lr = c >> 6, lc = c & 63;
        L[lr][lc] = f32 ? f2bf(((const float*)src)[(size_t)(r0 + lr) * C + c0 + lc])
                        : ((const __hip_bfloat16*)src)[(size_t)(r0 + lr) * C + c0 + lc];
    }
    __syncthreads();
    for (int c = t; c < 4096; c += 256) {
        int lr = c >> 6, lc = c & 63;
        dst[(size_t)(c0 + lr) * R + r0 + lc] = L[lc][lr];
    }
}

// ---------------- GEMM: 128x128 tile, BK=64, 2-phase staging, direct-store epilogue ----------------
// BIAS=0: partial GEMM over [z*ksplit, ...), C offset by z*NB, no bias. K, ksplit multiples of 64.
template<int ACT, int BIAS>
__global__ __launch_bounds__(256) void gemm_bt_lds_kernel(
    const __hip_bfloat16* __restrict__ A,
    const __hip_bfloat16* __restrict__ Bt,
    const __hip_bfloat16* __restrict__ bias,
    __hip_bfloat16* __restrict__ C,
    int M, int N, int K, int ksplit)
{
    const int bm = blockIdx.x * 128;
    const int bn = blockIdx.y * 128;
    int kbeg = 0, kend = K;
    if (BIAS == 0) {
        kbeg = blockIdx.z * ksplit;
        kend = kbeg + ksplit;
        C += (size_t)blockIdx.z * NB;
    }
    const int t = threadIdx.x;
    const int wave = t >> 6, lane = t & 63;
    const int wm = (wave >> 1) * 64, wn = (wave & 1) * 64;
    const int quad = lane >> 4, r = lane & 15;

    __shared__ alignas(16) __hip_bfloat16 As[2][128 * 32];
    __shared__ alignas(16) __hip_bfloat16 Bs[2][128 * 32];

    floatx4 acc[4][4];
    #pragma unroll
    for (int i = 0; i < 4; ++i)
        #pragma unroll
        for (int j = 0; j < 4; ++j)
            acc[i][j] = (floatx4){0.f, 0.f, 0.f, 0.f};

    const int c0 = wave * 128;

    for (int kt = kbeg; kt < kend; kt += 64) {
        #pragma unroll
        for (int h = 0; h < 2; ++h) {
            #pragma unroll
            for (int it = 0; it < 2; ++it) {
                int c = c0 + it * 64 + lane;
                int row = c >> 2, col = (c & 3) * 8;
                async_copy16(A + (size_t)(bm + row) * K + kt + h * 32 + col,
                             As[h] + (size_t)(c0 + it * 64) * 8);
                async_copy16(Bt + (size_t)(bn + row) * K + kt + h * 32 + col,
                             Bs[h] + (size_t)(c0 + it * 64) * 8);
            }
        }
        __syncthreads();
        #pragma unroll
        for (int h = 0; h < 2; ++h) {
            short8 af[4], bfr[4];
            #pragma unroll
            for (int i = 0; i < 4; ++i)
                af[i] = *reinterpret_cast<const short8*>(&As[h][(wm + i * 16 + r) * 32 + quad * 8]);
            #pragma unroll
            for (int j = 0; j < 4; ++j)
                bfr[j] = *reinterpret_cast<const short8*>(&Bs[h][(wn + j * 16 + r) * 32 + quad * 8]);
            #pragma unroll
            for (int i = 0; i < 4; ++i)
                #pragma unroll
                for (int j = 0; j < 4; ++j)
                    acc[i][j] = __builtin_amdgcn_mfma_f32_16x16x32_bf16(af[i], bfr[j], acc[i][j], 0, 0, 0);
        }
        __syncthreads();
    }

    #pragma unroll
    for (int j = 0; j < 4; ++j) {
        const int n = bn + wn + j * 16 + r;
        float bvv = BIAS ? bf2f(bias[n]) : 0.f;
        #pragma unroll
        for (int i = 0; i < 4; ++i) {
            #pragma unroll
            for (int v = 0; v < 4; ++v) {
                int m = bm + wm + i * 16 + quad * 4 + v;
                float x = acc[i][j][v] + bvv;
                if (ACT == 1) x = gelu_f(x);
                C[(size_t)m * N + n] = f2bf(x);
            }
        }
    }
}

// ---------------- fused QKV GEMM (BK=64, 2-phase, direct-store epilogue) ----------------
__global__ __launch_bounds__(256) void gemm_qkv_fused_kernel(
    const __hip_bfloat16* __restrict__ Acat,
    const __hip_bfloat16* __restrict__ Wcat,
    const __hip_bfloat16* __restrict__ biascat,
    __hip_bfloat16* __restrict__ Ocat)
{
    const int sel = blockIdx.x >> 6;
    const __hip_bfloat16* A = Acat + (size_t)sel * NB;
    const __hip_bfloat16* Bt = Wcat + (size_t)sel * 512 * 512;
    const __hip_bfloat16* bias = biascat + sel * 512;
    __hip_bfloat16* C = Ocat + (size_t)sel * NB;

    const int bm = (blockIdx.x & 63) * 128;
    const int bn = blockIdx.y * 128;
    const int t = threadIdx.x;
    const int wave = t >> 6, lane = t & 63;
    const int wm = (wave >> 1) * 64, wn = (wave & 1) * 64;
    const int quad = lane >> 4, r = lane & 15;
    const int K = EMBED, N = EMBED;

    __shared__ alignas(16) __hip_bfloat16 As[2][128 * 32];
    __shared__ alignas(16) __hip_bfloat16 Bs[2][128 * 32];

    floatx4 acc[4][4];
    #pragma unroll
    for (int i = 0; i < 4; ++i)
        #pragma unroll
        for (int j = 0; j < 4; ++j)
            acc[i][j] = (floatx4){0.f, 0.f, 0.f, 0.f};

    const int c0 = wave * 128;

    for (int kt = 0; kt < K; kt += 64) {
        #pragma unroll
        for (int h = 0; h < 2; ++h) {
            #pragma unroll
            for (int it = 0; it < 2; ++it) {
                int c = c0 + it * 64 + lane;
                int row = c >> 2, col = (c & 3) * 8;
                async_copy16(A + (size_t)(bm + row) * K + kt + h * 32 + col,
                             As[h] + (size_t)(c0 + it * 64) * 8);
                async_copy16(Bt + (size_t)(bn + row) * K + kt + h * 32 + col,
                             Bs[h] + (size_t)(c0 + it * 64) * 8);
            }
        }
        __syncthreads();
        #pragma unroll
        for (int h = 0; h < 2; ++h) {
            short8 af[4], bfr[4];
            #pragma unroll
            for (int i = 0; i < 4; ++i)
                af[i] = *reinterpret_cast<const short8*>(&As[h][(wm + i * 16 + r) * 32 + quad * 8]);
            #pragma unroll
            for (int j = 0; j < 4; ++j)
                bfr[j] = *reinterpret_cast<const short8*>(&Bs[h][(wn + j * 16 + r) * 32 + quad * 8]);
            #pragma unroll
            for (int i = 0; i < 4; ++i)
                #pragma unroll
                for (int j = 0; j < 4; ++j)
                    acc[i][j] = __builtin_amdgcn_mfma_f32_16x16x32_bf16(af[i], bfr[j], acc[i][j], 0, 0, 0);
        }
        __syncthreads();
    }

    #pragma unroll
    for (int j = 0; j < 4; ++j) {
        const int n = bn + wn + j * 16 + r;
        const float bvv = bf2f(bias[n]);
        #pragma unroll
        for (int i = 0; i < 4; ++i) {
            #pragma unroll
            for (int v = 0; v < 4; ++v) {
                int m = bm + wm + i * 16 + quad * 4 + v;
                C[(size_t)m * N + n] = f2bf(acc[i][j][v] + bvv);
            }
        }
    }
}

// ---------------- FFN1 GEMM: 256x256 tile, BK=64, minimal-2-phase dbuf prefetch ----------------
// 512 threads = 8 waves (2M x 4N), per-wave 128x64 output. LDS 128KB -> 1 block/CU.
// Next tile's global_load_lds issued BEFORE current compute; single barrier per tile
// (T3-minimum, m230-validated structure). Epilogue: bias + gelu, direct stores.
__global__ __launch_bounds__(512, 2) void gemm_ffn1_256_kernel(
    const __hip_bfloat16* __restrict__ A,    // [8192][512]
    const __hip_bfloat16* __restrict__ Bt,   // W1T [2048][512]
    const __hip_bfloat16* __restrict__ bias, // [2048]
    __hip_bfloat16* __restrict__ C)          // [8192][2048]
{
    const int bm = blockIdx.x * 256;
    const int bn = blockIdx.y * 256;
    const int K = EMBED, N = FFN;
    const int t = threadIdx.x;
    const int wave = t >> 6, lane = t & 63;
    const int wmi = wave >> 2, wni = wave & 3;       // 2M x 4N
    const int wm = wmi * 128, wn = wni * 64;
    const int quad = lane >> 4, r = lane & 15;

    __shared__ alignas(16) __hip_bfloat16 As[2][2][256 * 32];  // [buf][half]
    __shared__ alignas(16) __hip_bfloat16 Bs[2][2][256 * 32];

    floatx4 acc[8][4];
    #pragma unroll
    for (int i = 0; i < 8; ++i)
        #pragma unroll
        for (int j = 0; j < 4; ++j)
            acc[i][j] = (floatx4){0.f, 0.f, 0.f, 0.f};

    auto stage = [&](int d, int kt) {
        #pragma unroll
        for (int h = 0; h < 2; ++h) {
            #pragma unroll
            for (int it = 0; it < 2; ++it) {
                int c = wave * 128 + it * 64 + lane;     // chunk index [0,1024)
                int row = c >> 2, col = (c & 3) * 8;
                async_copy16(A + (size_t)(bm + row) * K + kt + h * 32 + col,
                             As[d][h] + (size_t)(wave * 128 + it * 64) * 8);
                async_copy16(Bt + (size_t)(bn + row) * K + kt + h * 32 + col,
                             Bs[d][h] + (size_t)(wave * 128 + it * 64) * 8);
            }
        }
    };

    stage(0, 0);
    __syncthreads();

    int cur = 0;
    for (int kt = 0; kt < K; kt += 64) {
        if (kt + 64 < K) stage(cur ^ 1, kt + 64);
        #pragma unroll
        for (int h = 0; h < 2; ++h) {
            short8 af[8], bfr[4];
            #pragma unroll
            for (int i = 0; i < 8; ++i)
                af[i] = *reinterpret_cast<const short8*>(&As[cur][h][(wm + i * 16 + r) * 32 + quad * 8]);
            #pragma unroll
            for (int j = 0; j < 4; ++j)
                bfr[j] = *reinterpret_cast<const short8*>(&Bs[cur][h][(wn + j * 16 + r) * 32 + quad * 8]);
            __builtin_amdgcn_s_setprio(1);
            #pragma unroll
            for (int i = 0; i < 8; ++i)
                #pragma unroll
                for (int j = 0; j < 4; ++j)
                    acc[i][j] = __builtin_amdgcn_mfma_f32_16x16x32_bf16(af[i], bfr[j], acc[i][j], 0, 0, 0);
            __builtin_amdgcn_s_setprio(0);
        }
        __syncthreads();
        cur ^= 1;
    }

    #pragma unroll
    for (int j = 0; j < 4; ++j) {
        const int n = bn + wn + j * 16 + r;
        const float bvv = bf2f(bias[n]);
        #pragma unroll
        for (int i = 0; i < 8; ++i) {
            #pragma unroll
            for (int v = 0; v < 4; ++v) {
                int m = bm + wm + i * 16 + quad * 4 + v;
                C[(size_t)m * N + n] = f2bf(gelu_f(acc[i][j][v] + bvv));
            }
        }
    }
}

// ---------------- V head-transpose: Vb[B*S][E] -> Vt[B*H][64 d][2048 s] ----------------
__global__ __launch_bounds__(256) void vtrans_kernel(
    const __hip_bfloat16* __restrict__ Vb, __hip_bfloat16* __restrict__ Vt)
{
    const int bh = blockIdx.y;
    const int b = bh >> 3, h = bh & 7;
    const int s0 = blockIdx.x * 64;
    __shared__ alignas(16) __hip_bfloat16 L[64][72];
    const int t = threadIdx.x;
    for (int c = t; c < 512; c += 256) {
        int row = c >> 3, g = c & 7;
        *reinterpret_cast<uint4*>(&L[row][g * 8]) =
            *reinterpret_cast<const uint4*>(Vb + (size_t)(b * SS + s0 + row) * EMBED + h * 64 + g * 8);
    }
    __syncthreads();
    for (int c = t; c < 512; c += 256) {
        int d = c >> 3, g = c & 7;
        alignas(16) __hip_bfloat16 tmp[8];
        #pragma unroll
        for (int j = 0; j < 8; ++j) tmp[j] = L[g * 8 + j][d];
        *reinterpret_cast<uint4*>(Vt + ((size_t)bh * 64 + d) * SS + s0 + g * 8) =
            *reinterpret_cast<const uint4*>(tmp);
    }
}

// ---------------- MFMA flash attention: no-max softmax, l via MFMA, full-K ----------------
// grid (S/128, B*H). Wave w owns 32 queries (2 sets of 16). Scores bounded
// (|s|<~40 in base-2) so fixed m=0 is numerically safe. Each block covers the
// whole K-range, so l is complete in-register: normalize in epilogue, write
// ctx directly. K/V LDS double-buffered; next tile's global_load_lds issued
// BEFORE current compute (single barrier per tile).
__global__ __launch_bounds__(256) void attn_mfma_kernel(
    const __hip_bfloat16* __restrict__ Qg,
    const __hip_bfloat16* __restrict__ Kg,
    const __hip_bfloat16* __restrict__ Vt,
    __hip_bfloat16* __restrict__ ctx)
{
    const int bh = blockIdx.y;
    const int b = bh >> 3, h = bh & 7;
    const int q0 = blockIdx.x * 128;
    const int t = threadIdx.x;
    const int w = t >> 6, lane = t & 63;
    const int quad = lane >> 4, r = lane & 15;

    __shared__ alignas(16) __hip_bfloat16 Ks[2][2][64 * 32];   // [buf][slab]
    __shared__ alignas(16) __hip_bfloat16 Vs[2][2][64 * 32];
    __shared__ alignas(16) __hip_bfloat16 Ps[4][32][72];

    const size_t bbase = (size_t)b * SS * EMBED;
    const size_t hoff = (size_t)h * HDIM;
    const size_t vtbase = (size_t)bh * HDIM * SS;

    // Q fragments for 2 q-sets, pre-scaled by 0.125*log2(e)
    short8 aq[2][2];
    #pragma unroll
    for (int s = 0; s < 2; ++s) {
        const __hip_bfloat16* qrow = Qg + bbase + (size_t)(q0 + w * 32 + s * 16 + r) * EMBED + hoff;
        short8 t0 = *reinterpret_cast<const short8*>(qrow + quad * 8);
        short8 t1 = *reinterpret_cast<const short8*>(qrow + 32 + quad * 8);
        #pragma unroll
        for (int i = 0; i < 8; ++i) {
            ((__hip_bfloat16*)&aq[s][0])[i] = f2bf(bf2f(((const __hip_bfloat16*)&t0)[i]) * QSCALE);
            ((__hip_bfloat16*)&aq[s][1])[i] = f2bf(bf2f(((const __hip_bfloat16*)&t1)[i]) * QSCALE);
        }
    }

    // ones B-fragment for row-sum MFMA (bf16 1.0 = 0x3F80)
    const short one = 0x3F80;
    const short8 bones = {one, one, one, one, one, one, one, one};

    const int tensor = w >> 1, slab = w & 1;
    const int srow = lane >> 2;
    const int scol = (((lane & 3) ^ ((srow >> 1) & 3)) * 8);
    const int cs = ((r >> 1) & 3) * 8;

    floatx4 o0[4], o1[4], l0a, l1a;
    #pragma unroll
    for (int nt = 0; nt < 4; ++nt) {
        o0[nt] = (floatx4){0.f, 0.f, 0.f, 0.f};
        o1[nt] = (floatx4){0.f, 0.f, 0.f, 0.f};
    }
    l0a = (floatx4){0.f, 0.f, 0.f, 0.f};
    l1a = (floatx4){0.f, 0.f, 0.f, 0.f};

    const __hip_bfloat16* kp[4];
    const __hip_bfloat16* vp[4];
    #pragma unroll
    for (int g = 0; g < 4; ++g) {
        int row = g * 16 + srow;
        kp[g] = Kg + bbase + (size_t)row * EMBED + hoff + slab * 32 + scol;
        vp[g] = Vt + vtbase + (size_t)row * SS + slab * 32 + scol;
    }

    if (tensor == 0) {
        #pragma unroll
        for (int g = 0; g < 4; ++g) {
            async_copy16(kp[g], &Ks[0][slab][g * 512]);
            kp[g] += 64 * EMBED;
        }
    } else {
        #pragma unroll
        for (int g = 0; g < 4; ++g) {
            async_copy16(vp[g], &Vs[0][slab][g * 512]);
            vp[g] += 64;
        }
    }
    __syncthreads();

    int cur = 0;
    for (int kt = 0; kt < SS; kt += 64) {
        if (kt + 64 < SS) {
            if (tensor == 0) {
                #pragma unroll
                for (int g = 0; g < 4; ++g) {
                    async_copy16(kp[g], &Ks[cur ^ 1][slab][g * 512]);
                    kp[g] += 64 * EMBED;
                }
            } else {
                #pragma unroll
                for (int g = 0; g < 4; ++g) {
                    async_copy16(vp[g], &Vs[cur ^ 1][slab][g * 512]);
                    vp[g] += 64;
                }
            }
        }

        floatx4 s0[4], s1[4];
        #pragma unroll
        for (int nt = 0; nt < 4; ++nt) {
            s0[nt] = (floatx4){0.f, 0.f, 0.f, 0.f};
            s1[nt] = (floatx4){0.f, 0.f, 0.f, 0.f};
        }
        __builtin_amdgcn_s_setprio(1);
        #pragma unroll
        for (int nt = 0; nt < 4; ++nt) {
            short8 ak0 = *reinterpret_cast<const short8*>(&Ks[cur][0][(nt * 16 + r) * 32 + (quad * 8 ^ cs)]);
            short8 ak1 = *reinterpret_cast<const short8*>(&Ks[cur][1][(nt * 16 + r) * 32 + (quad * 8 ^ cs)]);
            s0[nt] = __builtin_amdgcn_mfma_f32_16x16x32_bf16(ak0, aq[0][0], s0[nt], 0, 0, 0);
            s0[nt] = __builtin_amdgcn_mfma_f32_16x16x32_bf16(ak1, aq[0][1], s0[nt], 0, 0, 0);
            s1[nt] = __builtin_amdgcn_mfma_f32_16x16x32_bf16(ak0, aq[1][0], s1[nt], 0, 0, 0);
            s1[nt] = __builtin_amdgcn_mfma_f32_16x16x32_bf16(ak1, aq[1][1], s1[nt], 0, 0, 0);
        }
        __builtin_amdgcn_s_setprio(0);

        #pragma unroll
        for (int s = 0; s < 2; ++s) {
            floatx4* sc = s == 0 ? s0 : s1;
            #pragma unroll
            for (int nt = 0; nt < 4; ++nt) {
                float p0 = exp2f(sc[nt][0]), p1 = exp2f(sc[nt][1]);
                float p2 = exp2f(sc[nt][2]), p3 = exp2f(sc[nt][3]);
                __hip_bfloat162 pa = __float22bfloat162_rn(make_float2(p0, p1));
                __hip_bfloat162 pb = __float22bfloat162_rn(make_float2(p2, p3));
                uint2 u;
                u.x = *reinterpret_cast<unsigned*>(&pa);
                u.y = *reinterpret_cast<unsigned*>(&pb);
                *reinterpret_cast<uint2*>(&Ps[w][s * 16 + r][nt * 16 + quad * 4]) = u;
            }
        }

        short8 ap00 = *reinterpret_cast<const short8*>(&Ps[w][r][quad * 8]);
        short8 ap01 = *reinterpret_cast<const short8*>(&Ps[w][r][32 + quad * 8]);
        short8 ap10 = *reinterpret_cast<const short8*>(&Ps[w][16 + r][quad * 8]);
        short8 ap11 = *reinterpret_cast<const short8*>(&Ps[w][16 + r][32 + quad * 8]);
        __builtin_amdgcn_s_setprio(1);
        #pragma unroll
        for (int nt = 0; nt < 4; ++nt) {
            short8 bv0 = *reinterpret_cast<const short8*>(&Vs[cur][0][(nt * 16 + r) * 32 + (quad * 8 ^ cs)]);
            short8 bv1 = *reinterpret_cast<const short8*>(&Vs[cur][1][(nt * 16 + r) * 32 + (quad * 8 ^ cs)]);
            o0[nt] = __builtin_amdgcn_mfma_f32_16x16x32_bf16(ap00, bv0, o0[nt], 0, 0, 0);
            o0[nt] = __builtin_amdgcn_mfma_f32_16x16x32_bf16(ap01, bv1, o0[nt], 0, 0, 0);
            o1[nt] = __builtin_amdgcn_mfma_f32_16x16x32_bf16(ap10, bv0, o1[nt], 0, 0, 0);
            o1[nt] = __builtin_amdgcn_mfma_f32_16x16x32_bf16(ap11, bv1, o1[nt], 0, 0, 0);
        }
        l0a = __builtin_amdgcn_mfma_f32_16x16x32_bf16(ap00, bones, l0a, 0, 0, 0);
        l0a = __builtin_amdgcn_mfma_f32_16x16x32_bf16(ap01, bones, l0a, 0, 0, 0);
        l1a = __builtin_amdgcn_mfma_f32_16x16x32_bf16(ap10, bones, l1a, 0, 0, 0);
        l1a = __builtin_amdgcn_mfma_f32_16x16x32_bf16(ap11, bones, l1a, 0, 0, 0);
        __builtin_amdgcn_s_setprio(0);

        __syncthreads();
        cur ^= 1;
    }

    #pragma unroll
    for (int s = 0; s < 2; ++s) {
        floatx4* oa = s == 0 ? o0 : o1;
        floatx4 la = s == 0 ? l0a : l1a;
        #pragma unroll
        for (int v = 0; v < 4; ++v) {
            int q = q0 + w * 32 + s * 16 + quad * 4 + v;
            float inv = 1.0f / la[v];
            __hip_bfloat16* orow = ctx + bbase + (size_t)q * EMBED + hoff;
            #pragma unroll
            for (int nt = 0; nt < 4; ++nt)
                orow[nt * 16 + r] = f2bf(oa[nt][v] * inv);
        }
    }
}

// ---------------- fused residual-add + LayerNorm (split-K Y partials) ----------------
template<int OUT32>
__global__ __launch_bounds__(256) void add_ln_split_kernel(
    const __hip_bfloat16* __restrict__ X,
    const __hip_bfloat16* __restrict__ Y0,
    const __hip_bfloat16* __restrict__ Y1,
    const __hip_bfloat16* __restrict__ bias,
    const __hip_bfloat16* __restrict__ g,
    const __hip_bfloat16* __restrict__ bt,
    void* __restrict__ out,
    const int* __restrict__ dflag)
{
    const int w = threadIdx.x >> 6, lane = threadIdx.x & 63;
    const int row = blockIdx.x * 4 + w;
    const size_t base = (size_t)row * EMBED + lane * 8;
    const int co = lane * 8;

    short8 xv  = *reinterpret_cast<const short8*>(X + base);
    short8 y0v = *reinterpret_cast<const short8*>(Y0 + base);
    short8 y1v = *reinterpret_cast<const short8*>(Y1 + base);
    short8 bv  = *reinterpret_cast<const short8*>(bias + co);

    float x[8];
    float s = 0.f;
    #pragma unroll
    for (int j = 0; j < 8; ++j) {
        x[j] = bf2f(((const __hip_bfloat16*)&xv)[j]) + bf2f(((const __hip_bfloat16*)&y0v)[j])
             + bf2f(((const __hip_bfloat16*)&y1v)[j]) + bf2f(((const __hip_bfloat16*)&bv)[j]);
        s += x[j];
    }
    #pragma unroll
    for (int off = 32; off; off >>= 1) s += __shfl_xor(s, off, 64);
    const float mu = s * (1.0f / EMBED);
    float vs = 0.f;
    #pragma unroll
    for (int j = 0; j < 8; ++j) { x[j] -= mu; vs += x[j] * x[j]; }
    #pragma unroll
    for (int off = 32; off; off >>= 1) vs += __shfl_xor(vs, off, 64);
    const float rstd = rsqrtf(vs * (1.0f / EMBED) + LN_EPS);

    short8 gv  = *reinterpret_cast<const short8*>(g + co);
    short8 btv = *reinterpret_cast<const short8*>(bt + co);
    if (OUT32 && *dflag) {
        float4 o0, o1;
        float of[8];
        #pragma unroll
        for (int j = 0; j < 8; ++j)
            of[j] = x[j] * rstd * bf2f(((const __hip_bfloat16*)&gv)[j]) + bf2f(((const __hip_bfloat16*)&btv)[j]);
        o0 = make_float4(of[0], of[1], of[2], of[3]);
        o1 = make_float4(of[4], of[5], of[6], of[7]);
        *reinterpret_cast<float4*>((float*)out + base) = o0;
        *reinterpret_cast<float4*>((float*)out + base + 4) = o1;
    } else {
        alignas(16) __hip_bfloat16 o[8];
        #pragma unroll
        for (int j = 0; j < 8; ++j)
            o[j] = f2bf(x[j] * rstd * bf2f(((const __hip_bfloat16*)&gv)[j]) + bf2f(((const __hip_bfloat16*)&btv)[j]));
        *reinterpret_cast<uint4*>((__hip_bfloat16*)out + base) = *reinterpret_cast<const uint4*>(o);
    }
}

// ---------------- launch ----------------
extern "C" void kernel_launch(void* const* d_in, const int* in_sizes, int n_in,
                              void* d_out, int out_size, void* d_ws, size_t ws_size,
                              hipStream_t stream)
{
    (void)in_sizes; (void)n_in; (void)out_size; (void)ws_size;

    const void* query = d_in[0];
    const void* keyi  = d_in[1];
    const void* vali  = d_in[2];
    const void* Wq = d_in[3];  const void* bq = d_in[4];
    const void* Wk = d_in[5];  const void* bk = d_in[6];
    const void* Wv = d_in[7];  const void* bv = d_in[8];
    const void* Wo = d_in[9];  const void* bo = d_in[10];
    const void* g1 = d_in[11]; const void* be1 = d_in[12];
    const void* g2 = d_in[13]; const void* be2 = d_in[14];
    const void* W1 = d_in[15]; const void* b1 = d_in[16];
    const void* W2 = d_in[17]; const void* b2 = d_in[18];

    // ws: 64B flag | 16KB biasb | 6MB Wcat | 8 x 8MB units (~70MB, proven)
    int* dflag = (int*)d_ws;
    __hip_bfloat16* biasb = (__hip_bfloat16*)((char*)d_ws + 64);
    __hip_bfloat16* Wcat = biasb + 8192;
    __hip_bfloat16* buf = Wcat + 4 * 512 * 512 + 2 * 512 * 2048;
    __hip_bfloat16* bqkvb = biasb;
    __hip_bfloat16* bob  = biasb + 1536;
    __hip_bfloat16* b1b  = biasb + 2048;
    __hip_bfloat16* b2b  = biasb + 4096;
    __hip_bfloat16* g1b  = biasb + 4608;
    __hip_bfloat16* be1b = biasb + 5120;
    __hip_bfloat16* g2b  = biasb + 5632;
    __hip_bfloat16* be2b = biasb + 6144;
    // units
    __hip_bfloat16* qkvbf  = buf;                  // 0..2 (qbf live till LN1)
    __hip_bfloat16* QKVo   = buf + 3 * NB;         // 3..5
    __hip_bfloat16* Qb = QKVo;
    __hip_bfloat16* Kb = QKVo + NB;
    __hip_bfloat16* Vb = QKVo + 2 * NB;
    __hip_bfloat16* Vt     = buf + 1 * NB;         // kbf dead after QKV
    __hip_bfloat16* ctx    = buf + 2 * NB;         // vbf dead after QKV
    __hip_bfloat16* Yw     = buf + 4 * NB;         // Wo partials: units 4,5 (Kb,Vb dead after attn)
    __hip_bfloat16* x1     = buf + 3 * NB;         // Qb dead after attn
    __hip_bfloat16* hbf    = buf + 4 * NB;         // FFN1 out: units 4..7 (Vt dead after attn)
    __hip_bfloat16* Yf     = buf + 1 * NB;         // FFN2 partials: units 1,2

    prep_kernel<<<6913, 256, 0, stream>>>(
        query, keyi, vali, Wq, Wk, Wv, Wo, W1, W2,
        bq, bk, bv, bo, b1, b2, g1, be1, g2, be2,
        qkvbf, Wcat, biasb, dflag);

    gemm_qkv_fused_kernel<<<dim3(192, 4), 256, 0, stream>>>(qkvbf, Wcat, bqkvb, QKVo);

    vtrans_kernel<<<dim3(SS / 64, BB * NHEAD), 256, 0, stream>>>(Vb, Vt);

    attn_mfma_kernel<<<dim3(SS / 128, BB * NHEAD), 256, 0, stream>>>(
        Qb, Kb, Vt, ctx);

    // Wo projection split-K2 (partials, bias folded into LN1)
    gemm_bt_lds_kernel<0, 0><<<dim3(MROWS / 128, EMBED / 128, 2), 256, 0, stream>>>(
        ctx, Wcat + 3 * 512 * 512, nullptr, Yw, MROWS, EMBED, EMBED, EMBED / 2);
    add_ln_split_kernel<0><<<MROWS / 4, 256, 0, stream>>>(
        qkvbf, Yw, Yw + NB, bob, g1b, be1b, x1, dflag);

    // FFN
    gemm_ffn1_256_kernel<<<dim3(MROWS / 256, FFN / 256), 512, 0, stream>>>(
        x1, Wcat + 4 * 512 * 512, b1b, hbf);
    gemm_bt_lds_kernel<0, 0><<<dim3(MROWS / 128, EMBED / 128, 2), 256, 0, stream>>>(
        hbf, Wcat + 4 * 512 * 512 + 512 * 2048, nullptr, Yf, MROWS, EMBED, FFN, FFN / 2);
    add_ln_split_kernel<1><<<MROWS / 4, 256, 0, stream>>>(
        x1, Yf, Yf + NB, b2b, g2b, be2b, d_out, dflag);
}

// Round 9
// 318.314 us; speedup vs baseline: 1.0688x; 1.0688x over previous
//
#include <hip/hip_runtime.h>
#include <hip/hip_bf16.h>
#include <math.h>

// Problem constants
#define EMBED 512
#define NHEAD 8
#define HDIM 64
#define FFN 2048
#define BB 4
#define SS 2048
#define MROWS (BB*SS)   // 8192
#define NB ((size_t)MROWS * EMBED)   // 4M elems = 2^22
#define LN_EPS 1e-5f
#define QSCALE 0.180336880111f   // 0.125 * log2(e)

typedef __attribute__((ext_vector_type(8))) short short8;
typedef __attribute__((ext_vector_type(4))) float floatx4;

__device__ inline float bf2f(__hip_bfloat16 x) { return __bfloat162float(x); }
__device__ inline __hip_bfloat16 f2bf(float x) { return __float2bfloat16(x); }

__device__ inline float gelu_f(float x) {
    return 0.5f * x * (1.0f + erff(x * 0.70710678118654752f));
}

__device__ inline void async_copy16(const void* g, void* l) {
    __builtin_amdgcn_global_load_lds(
        (const __attribute__((address_space(1))) void*)g,
        (__attribute__((address_space(3))) void*)l, 16, 0, 0);
}

__device__ inline int sane_f(float v) {
    return (v == v) && (fabsf(v) > 0x1p-40f) && (fabsf(v) < 0x1p40f);
}

// ---------------- fused prep: qkv cvt + all weight transposes + bias cvt + dtype detect ----------------
__global__ __launch_bounds__(256) void prep_kernel(
    const void* __restrict__ query, const void* __restrict__ keyi, const void* __restrict__ vali,
    const void* __restrict__ Wq, const void* __restrict__ Wk, const void* __restrict__ Wv,
    const void* __restrict__ Wo, const void* __restrict__ W1, const void* __restrict__ W2,
    const void* __restrict__ bq, const void* __restrict__ bk, const void* __restrict__ bv,
    const void* __restrict__ bo, const void* __restrict__ b1, const void* __restrict__ b2,
    const void* __restrict__ g1, const void* __restrict__ be1,
    const void* __restrict__ g2, const void* __restrict__ be2,
    __hip_bfloat16* __restrict__ qkvbf,
    __hip_bfloat16* __restrict__ Wcat,     // WqT|WkT|WvT|WoT|W1T|W2T
    __hip_bfloat16* __restrict__ biasb,
    int* __restrict__ dflag)
{
    __shared__ __hip_bfloat16 L[64][65];
    const int f32 = sane_f(((const float*)query)[7]) + sane_f(((const float*)query)[1031]) +
                    sane_f(((const float*)query)[200003]) + sane_f(((const float*)query)[1000003]) >= 3;
    const int t = threadIdx.x;
    const int blk = blockIdx.x;

    if (blk < 6144) {   // qkv convert, 8 elems/thread
        size_t pos = ((size_t)blk * 256 + t) * 8;
        int sel = (int)(pos >> 22);
        size_t off = pos & (NB - 1);
        const void* src = sel == 0 ? query : sel == 1 ? keyi : vali;
        if (f32) {
            const float* s = (const float*)src + off;
            float4 f0 = *reinterpret_cast<const float4*>(s);
            float4 f1 = *reinterpret_cast<const float4*>(s + 4);
            alignas(16) __hip_bfloat16 h[8] = {
                f2bf(f0.x), f2bf(f0.y), f2bf(f0.z), f2bf(f0.w),
                f2bf(f1.x), f2bf(f1.y), f2bf(f1.z), f2bf(f1.w)};
            *reinterpret_cast<uint4*>(qkvbf + pos) = *reinterpret_cast<const uint4*>(h);
        } else {
            *reinterpret_cast<uint4*>(qkvbf + pos) =
                *reinterpret_cast<const uint4*>((const __hip_bfloat16*)src + off);
        }
        return;
    }

    const void* src; __hip_bfloat16* dst; int R, C, r0, c0;
    if (blk < 6400) {          // W1 [512][2048] -> W1T
        int b2i = blk - 6144; src = W1; dst = Wcat + 4 * 512 * 512;
        R = 512; C = 2048; r0 = (b2i >> 5) * 64; c0 = (b2i & 31) * 64;
    } else if (blk < 6656) {   // W2 [2048][512] -> W2T
        int b3 = blk - 6400; src = W2; dst = Wcat + 4 * 512 * 512 + 512 * 2048;
        R = 2048; C = 512; r0 = (b3 >> 3) * 64; c0 = (b3 & 7) * 64;
    } else if (blk < 6912) {   // Wq/Wk/Wv/Wo 512x512
        int b4 = blk - 6656; int which = b4 >> 6; int tile = b4 & 63;
        src = which == 0 ? Wq : which == 1 ? Wk : which == 2 ? Wv : Wo;
        dst = Wcat + (size_t)which * 512 * 512;
        R = 512; C = 512; r0 = (tile >> 3) * 64; c0 = (tile & 7) * 64;
    } else {                   // biases / ln params / dtype flag
        if (t == 0) *dflag = f32 ? 1 : 0;
        const void* srcs[10] = {bq, bk, bv, bo, b1, b2, g1, be1, g2, be2};
        const int offs[10] = {0, 512, 1024, 1536, 2048, 4096, 4608, 5120, 5632, 6144};
        const int lens[10] = {512, 512, 512, 512, 2048, 512, 512, 512, 512, 512};
        for (int a = 0; a < 10; ++a)
            for (int i = t; i < lens[a]; i += 256)
                biasb[offs[a] + i] = f32 ? f2bf(((const float*)srcs[a])[i])
                                         : ((const __hip_bfloat16*)srcs[a])[i];
        return;
    }
    for (int c = t; c < 4096; c += 256) {
        int lr = c >> 6, lc = c & 63;
        L[lr][lc] = f32 ? f2bf(((const float*)src)[(size_t)(r0 + lr) * C + c0 + lc])
                        : ((const __hip_bfloat16*)src)[(size_t)(r0 + lr) * C + c0 + lc];
    }
    __syncthreads();
    for (int c = t; c < 4096; c += 256) {
        int lr = c >> 6, lc = c & 63;
        dst[(size_t)(c0 + lr) * R + r0 + lc] = L[lc][lr];
    }
}

// ---------------- GEMM: 128x128 tile, BK=64, 2-phase staging, direct-store epilogue ----------------
// BIAS=0: partial GEMM over [z*ksplit, ...), C offset by z*NB, no bias. K, ksplit multiples of 64.
template<int ACT, int BIAS>
__global__ __launch_bounds__(256) void gemm_bt_lds_kernel(
    const __hip_bfloat16* __restrict__ A,
    const __hip_bfloat16* __restrict__ Bt,
    const __hip_bfloat16* __restrict__ bias,
    __hip_bfloat16* __restrict__ C,
    int M, int N, int K, int ksplit)
{
    const int bm = blockIdx.x * 128;
    const int bn = blockIdx.y * 128;
    int kbeg = 0, kend = K;
    if (BIAS == 0) {
        kbeg = blockIdx.z * ksplit;
        kend = kbeg + ksplit;
        C += (size_t)blockIdx.z * NB;
    }
    const int t = threadIdx.x;
    const int wave = t >> 6, lane = t & 63;
    const int wm = (wave >> 1) * 64, wn = (wave & 1) * 64;
    const int quad = lane >> 4, r = lane & 15;

    __shared__ alignas(16) __hip_bfloat16 As[2][128 * 32];
    __shared__ alignas(16) __hip_bfloat16 Bs[2][128 * 32];

    floatx4 acc[4][4];
    #pragma unroll
    for (int i = 0; i < 4; ++i)
        #pragma unroll
        for (int j = 0; j < 4; ++j)
            acc[i][j] = (floatx4){0.f, 0.f, 0.f, 0.f};

    const int c0 = wave * 128;

    for (int kt = kbeg; kt < kend; kt += 64) {
        #pragma unroll
        for (int h = 0; h < 2; ++h) {
            #pragma unroll
            for (int it = 0; it < 2; ++it) {
                int c = c0 + it * 64 + lane;
                int row = c >> 2, col = (c & 3) * 8;
                async_copy16(A + (size_t)(bm + row) * K + kt + h * 32 + col,
                             As[h] + (size_t)(c0 + it * 64) * 8);
                async_copy16(Bt + (size_t)(bn + row) * K + kt + h * 32 + col,
                             Bs[h] + (size_t)(c0 + it * 64) * 8);
            }
        }
        __syncthreads();
        #pragma unroll
        for (int h = 0; h < 2; ++h) {
            short8 af[4], bfr[4];
            #pragma unroll
            for (int i = 0; i < 4; ++i)
                af[i] = *reinterpret_cast<const short8*>(&As[h][(wm + i * 16 + r) * 32 + quad * 8]);
            #pragma unroll
            for (int j = 0; j < 4; ++j)
                bfr[j] = *reinterpret_cast<const short8*>(&Bs[h][(wn + j * 16 + r) * 32 + quad * 8]);
            #pragma unroll
            for (int i = 0; i < 4; ++i)
                #pragma unroll
                for (int j = 0; j < 4; ++j)
                    acc[i][j] = __builtin_amdgcn_mfma_f32_16x16x32_bf16(af[i], bfr[j], acc[i][j], 0, 0, 0);
        }
        __syncthreads();
    }

    #pragma unroll
    for (int j = 0; j < 4; ++j) {
        const int n = bn + wn + j * 16 + r;
        float bvv = BIAS ? bf2f(bias[n]) : 0.f;
        #pragma unroll
        for (int i = 0; i < 4; ++i) {
            #pragma unroll
            for (int v = 0; v < 4; ++v) {
                int m = bm + wm + i * 16 + quad * 4 + v;
                float x = acc[i][j][v] + bvv;
                if (ACT == 1) x = gelu_f(x);
                C[(size_t)m * N + n] = f2bf(x);
            }
        }
    }
}

// ---------------- fused QKV GEMM (BK=64, 2-phase) with V-transpose epilogue ----------------
// sel 0/1 write Q/K normally; sel 2 writes V directly in Vt[bh][d][s] layout
// (4 consecutive s per acc -> 8B packed stores), eliminating the vtrans pass.
// Stores are fire-and-forget (R5 lesson) so the scatter costs ~nothing; the win
// is the removed vtrans dispatch + 32MB round-trip (measured -5us, R7/R8 decomp).
__global__ __launch_bounds__(256) void gemm_qkv_fused_kernel(
    const __hip_bfloat16* __restrict__ Acat,
    const __hip_bfloat16* __restrict__ Wcat,
    const __hip_bfloat16* __restrict__ biascat,
    __hip_bfloat16* __restrict__ Ocat,
    __hip_bfloat16* __restrict__ Vt)
{
    const int sel = blockIdx.x >> 6;
    const __hip_bfloat16* A = Acat + (size_t)sel * NB;
    const __hip_bfloat16* Bt = Wcat + (size_t)sel * 512 * 512;
    const __hip_bfloat16* bias = biascat + sel * 512;
    __hip_bfloat16* C = Ocat + (size_t)sel * NB;

    const int bm = (blockIdx.x & 63) * 128;
    const int bn = blockIdx.y * 128;
    const int t = threadIdx.x;
    const int wave = t >> 6, lane = t & 63;
    const int wm = (wave >> 1) * 64, wn = (wave & 1) * 64;
    const int quad = lane >> 4, r = lane & 15;
    const int K = EMBED, N = EMBED;

    __shared__ alignas(16) __hip_bfloat16 As[2][128 * 32];
    __shared__ alignas(16) __hip_bfloat16 Bs[2][128 * 32];

    floatx4 acc[4][4];
    #pragma unroll
    for (int i = 0; i < 4; ++i)
        #pragma unroll
        for (int j = 0; j < 4; ++j)
            acc[i][j] = (floatx4){0.f, 0.f, 0.f, 0.f};

    const int c0 = wave * 128;

    for (int kt = 0; kt < K; kt += 64) {
        #pragma unroll
        for (int h = 0; h < 2; ++h) {
            #pragma unroll
            for (int it = 0; it < 2; ++it) {
                int c = c0 + it * 64 + lane;
                int row = c >> 2, col = (c & 3) * 8;
                async_copy16(A + (size_t)(bm + row) * K + kt + h * 32 + col,
                             As[h] + (size_t)(c0 + it * 64) * 8);
                async_copy16(Bt + (size_t)(bn + row) * K + kt + h * 32 + col,
                             Bs[h] + (size_t)(c0 + it * 64) * 8);
            }
        }
        __syncthreads();
        #pragma unroll
        for (int h = 0; h < 2; ++h) {
            short8 af[4], bfr[4];
            #pragma unroll
            for (int i = 0; i < 4; ++i)
                af[i] = *reinterpret_cast<const short8*>(&As[h][(wm + i * 16 + r) * 32 + quad * 8]);
            #pragma unroll
            for (int j = 0; j < 4; ++j)
                bfr[j] = *reinterpret_cast<const short8*>(&Bs[h][(wn + j * 16 + r) * 32 + quad * 8]);
            #pragma unroll
            for (int i = 0; i < 4; ++i)
                #pragma unroll
                for (int j = 0; j < 4; ++j)
                    acc[i][j] = __builtin_amdgcn_mfma_f32_16x16x32_bf16(af[i], bfr[j], acc[i][j], 0, 0, 0);
        }
        __syncthreads();
    }

    if (sel < 2) {
        #pragma unroll
        for (int j = 0; j < 4; ++j) {
            const int n = bn + wn + j * 16 + r;
            const float bvv = bf2f(bias[n]);
            #pragma unroll
            for (int i = 0; i < 4; ++i) {
                #pragma unroll
                for (int v = 0; v < 4; ++v) {
                    int m = bm + wm + i * 16 + quad * 4 + v;
                    C[(size_t)m * N + n] = f2bf(acc[i][j][v] + bvv);
                }
            }
        }
    } else {
        // V: write transposed. m -> (b, s); n -> (h, d). Vt[((b*8+h)*64+d)*SS + s].
        #pragma unroll
        for (int j = 0; j < 4; ++j) {
            const int n = bn + wn + j * 16 + r;
            const float bvv = bf2f(bias[n]);
            const int hh = n >> 6, d = n & 63;
            #pragma unroll
            for (int i = 0; i < 4; ++i) {
                int m0 = bm + wm + i * 16 + quad * 4;
                int b = m0 >> 11, s0 = m0 & 2047;
                alignas(8) __hip_bfloat16 o[4];
                #pragma unroll
                for (int v = 0; v < 4; ++v)
                    o[v] = f2bf(acc[i][j][v] + bvv);
                *reinterpret_cast<uint2*>(Vt + ((size_t)(b * 8 + hh) * 64 + d) * SS + s0) =
                    *reinterpret_cast<const uint2*>(o);
            }
        }
    }
}

// ---------------- MFMA flash attention: no-max softmax, l via MFMA, full-K ----------------
// grid (S/128, B*H). Wave w owns 32 queries (2 sets of 16). Scores bounded
// (|s|<~40 in base-2) so fixed m=0 is numerically safe. Each block covers the
// whole K-range, so l is complete in-register: normalize in epilogue, write
// ctx directly. K/V LDS double-buffered; next tile's global_load_lds issued
// BEFORE current compute (single barrier per tile).
__global__ __launch_bounds__(256) void attn_mfma_kernel(
    const __hip_bfloat16* __restrict__ Qg,
    const __hip_bfloat16* __restrict__ Kg,
    const __hip_bfloat16* __restrict__ Vt,
    __hip_bfloat16* __restrict__ ctx)
{
    const int bh = blockIdx.y;
    const int b = bh >> 3, h = bh & 7;
    const int q0 = blockIdx.x * 128;
    const int t = threadIdx.x;
    const int w = t >> 6, lane = t & 63;
    const int quad = lane >> 4, r = lane & 15;

    __shared__ alignas(16) __hip_bfloat16 Ks[2][2][64 * 32];   // [buf][slab]
    __shared__ alignas(16) __hip_bfloat16 Vs[2][2][64 * 32];
    __shared__ alignas(16) __hip_bfloat16 Ps[4][32][72];

    const size_t bbase = (size_t)b * SS * EMBED;
    const size_t hoff = (size_t)h * HDIM;
    const size_t vtbase = (size_t)bh * HDIM * SS;

    // Q fragments for 2 q-sets, pre-scaled by 0.125*log2(e)
    short8 aq[2][2];
    #pragma unroll
    for (int s = 0; s < 2; ++s) {
        const __hip_bfloat16* qrow = Qg + bbase + (size_t)(q0 + w * 32 + s * 16 + r) * EMBED + hoff;
        short8 t0 = *reinterpret_cast<const short8*>(qrow + quad * 8);
        short8 t1 = *reinterpret_cast<const short8*>(qrow + 32 + quad * 8);
        #pragma unroll
        for (int i = 0; i < 8; ++i) {
            ((__hip_bfloat16*)&aq[s][0])[i] = f2bf(bf2f(((const __hip_bfloat16*)&t0)[i]) * QSCALE);
            ((__hip_bfloat16*)&aq[s][1])[i] = f2bf(bf2f(((const __hip_bfloat16*)&t1)[i]) * QSCALE);
        }
    }

    // ones B-fragment for row-sum MFMA (bf16 1.0 = 0x3F80)
    const short one = 0x3F80;
    const short8 bones = {one, one, one, one, one, one, one, one};

    const int tensor = w >> 1, slab = w & 1;
    const int srow = lane >> 2;
    const int scol = (((lane & 3) ^ ((srow >> 1) & 3)) * 8);
    const int cs = ((r >> 1) & 3) * 8;

    floatx4 o0[4], o1[4], l0a, l1a;
    #pragma unroll
    for (int nt = 0; nt < 4; ++nt) {
        o0[nt] = (floatx4){0.f, 0.f, 0.f, 0.f};
        o1[nt] = (floatx4){0.f, 0.f, 0.f, 0.f};
    }
    l0a = (floatx4){0.f, 0.f, 0.f, 0.f};
    l1a = (floatx4){0.f, 0.f, 0.f, 0.f};

    const __hip_bfloat16* kp[4];
    const __hip_bfloat16* vp[4];
    #pragma unroll
    for (int g = 0; g < 4; ++g) {
        int row = g * 16 + srow;
        kp[g] = Kg + bbase + (size_t)row * EMBED + hoff + slab * 32 + scol;
        vp[g] = Vt + vtbase + (size_t)row * SS + slab * 32 + scol;
    }

    if (tensor == 0) {
        #pragma unroll
        for (int g = 0; g < 4; ++g) {
            async_copy16(kp[g], &Ks[0][slab][g * 512]);
            kp[g] += 64 * EMBED;
        }
    } else {
        #pragma unroll
        for (int g = 0; g < 4; ++g) {
            async_copy16(vp[g], &Vs[0][slab][g * 512]);
            vp[g] += 64;
        }
    }
    __syncthreads();

    int cur = 0;
    for (int kt = 0; kt < SS; kt += 64) {
        if (kt + 64 < SS) {
            if (tensor == 0) {
                #pragma unroll
                for (int g = 0; g < 4; ++g) {
                    async_copy16(kp[g], &Ks[cur ^ 1][slab][g * 512]);
                    kp[g] += 64 * EMBED;
                }
            } else {
                #pragma unroll
                for (int g = 0; g < 4; ++g) {
                    async_copy16(vp[g], &Vs[cur ^ 1][slab][g * 512]);
                    vp[g] += 64;
                }
            }
        }

        floatx4 s0[4], s1[4];
        #pragma unroll
        for (int nt = 0; nt < 4; ++nt) {
            s0[nt] = (floatx4){0.f, 0.f, 0.f, 0.f};
            s1[nt] = (floatx4){0.f, 0.f, 0.f, 0.f};
        }
        __builtin_amdgcn_s_setprio(1);
        #pragma unroll
        for (int nt = 0; nt < 4; ++nt) {
            short8 ak0 = *reinterpret_cast<const short8*>(&Ks[cur][0][(nt * 16 + r) * 32 + (quad * 8 ^ cs)]);
            short8 ak1 = *reinterpret_cast<const short8*>(&Ks[cur][1][(nt * 16 + r) * 32 + (quad * 8 ^ cs)]);
            s0[nt] = __builtin_amdgcn_mfma_f32_16x16x32_bf16(ak0, aq[0][0], s0[nt], 0, 0, 0);
            s0[nt] = __builtin_amdgcn_mfma_f32_16x16x32_bf16(ak1, aq[0][1], s0[nt], 0, 0, 0);
            s1[nt] = __builtin_amdgcn_mfma_f32_16x16x32_bf16(ak0, aq[1][0], s1[nt], 0, 0, 0);
            s1[nt] = __builtin_amdgcn_mfma_f32_16x16x32_bf16(ak1, aq[1][1], s1[nt], 0, 0, 0);
        }
        __builtin_amdgcn_s_setprio(0);

        #pragma unroll
        for (int s = 0; s < 2; ++s) {
            floatx4* sc = s == 0 ? s0 : s1;
            #pragma unroll
            for (int nt = 0; nt < 4; ++nt) {
                float p0 = exp2f(sc[nt][0]), p1 = exp2f(sc[nt][1]);
                float p2 = exp2f(sc[nt][2]), p3 = exp2f(sc[nt][3]);
                __hip_bfloat162 pa = __float22bfloat162_rn(make_float2(p0, p1));
                __hip_bfloat162 pb = __float22bfloat162_rn(make_float2(p2, p3));
                uint2 u;
                u.x = *reinterpret_cast<unsigned*>(&pa);
                u.y = *reinterpret_cast<unsigned*>(&pb);
                *reinterpret_cast<uint2*>(&Ps[w][s * 16 + r][nt * 16 + quad * 4]) = u;
            }
        }

        short8 ap00 = *reinterpret_cast<const short8*>(&Ps[w][r][quad * 8]);
        short8 ap01 = *reinterpret_cast<const short8*>(&Ps[w][r][32 + quad * 8]);
        short8 ap10 = *reinterpret_cast<const short8*>(&Ps[w][16 + r][quad * 8]);
        short8 ap11 = *reinterpret_cast<const short8*>(&Ps[w][16 + r][32 + quad * 8]);
        __builtin_amdgcn_s_setprio(1);
        #pragma unroll
        for (int nt = 0; nt < 4; ++nt) {
            short8 bv0 = *reinterpret_cast<const short8*>(&Vs[cur][0][(nt * 16 + r) * 32 + (quad * 8 ^ cs)]);
            short8 bv1 = *reinterpret_cast<const short8*>(&Vs[cur][1][(nt * 16 + r) * 32 + (quad * 8 ^ cs)]);
            o0[nt] = __builtin_amdgcn_mfma_f32_16x16x32_bf16(ap00, bv0, o0[nt], 0, 0, 0);
            o0[nt] = __builtin_amdgcn_mfma_f32_16x16x32_bf16(ap01, bv1, o0[nt], 0, 0, 0);
            o1[nt] = __builtin_amdgcn_mfma_f32_16x16x32_bf16(ap10, bv0, o1[nt], 0, 0, 0);
            o1[nt] = __builtin_amdgcn_mfma_f32_16x16x32_bf16(ap11, bv1, o1[nt], 0, 0, 0);
        }
        l0a = __builtin_amdgcn_mfma_f32_16x16x32_bf16(ap00, bones, l0a, 0, 0, 0);
        l0a = __builtin_amdgcn_mfma_f32_16x16x32_bf16(ap01, bones, l0a, 0, 0, 0);
        l1a = __builtin_amdgcn_mfma_f32_16x16x32_bf16(ap10, bones, l1a, 0, 0, 0);
        l1a = __builtin_amdgcn_mfma_f32_16x16x32_bf16(ap11, bones, l1a, 0, 0, 0);
        __builtin_amdgcn_s_setprio(0);

        __syncthreads();
        cur ^= 1;
    }

    #pragma unroll
    for (int s = 0; s < 2; ++s) {
        floatx4* oa = s == 0 ? o0 : o1;
        floatx4 la = s == 0 ? l0a : l1a;
        #pragma unroll
        for (int v = 0; v < 4; ++v) {
            int q = q0 + w * 32 + s * 16 + quad * 4 + v;
            float inv = 1.0f / la[v];
            __hip_bfloat16* orow = ctx + bbase + (size_t)q * EMBED + hoff;
            #pragma unroll
            for (int nt = 0; nt < 4; ++nt)
                orow[nt * 16 + r] = f2bf(oa[nt][v] * inv);
        }
    }
}

// ---------------- fused residual-add + LayerNorm (split-K Y partials) ----------------
template<int OUT32>
__global__ __launch_bounds__(256) void add_ln_split_kernel(
    const __hip_bfloat16* __restrict__ X,
    const __hip_bfloat16* __restrict__ Y0,
    const __hip_bfloat16* __restrict__ Y1,
    const __hip_bfloat16* __restrict__ bias,
    const __hip_bfloat16* __restrict__ g,
    const __hip_bfloat16* __restrict__ bt,
    void* __restrict__ out,
    const int* __restrict__ dflag)
{
    const int w = threadIdx.x >> 6, lane = threadIdx.x & 63;
    const int row = blockIdx.x * 4 + w;
    const size_t base = (size_t)row * EMBED + lane * 8;
    const int co = lane * 8;

    short8 xv  = *reinterpret_cast<const short8*>(X + base);
    short8 y0v = *reinterpret_cast<const short8*>(Y0 + base);
    short8 y1v = *reinterpret_cast<const short8*>(Y1 + base);
    short8 bv  = *reinterpret_cast<const short8*>(bias + co);

    float x[8];
    float s = 0.f;
    #pragma unroll
    for (int j = 0; j < 8; ++j) {
        x[j] = bf2f(((const __hip_bfloat16*)&xv)[j]) + bf2f(((const __hip_bfloat16*)&y0v)[j])
             + bf2f(((const __hip_bfloat16*)&y1v)[j]) + bf2f(((const __hip_bfloat16*)&bv)[j]);
        s += x[j];
    }
    #pragma unroll
    for (int off = 32; off; off >>= 1) s += __shfl_xor(s, off, 64);
    const float mu = s * (1.0f / EMBED);
    float vs = 0.f;
    #pragma unroll
    for (int j = 0; j < 8; ++j) { x[j] -= mu; vs += x[j] * x[j]; }
    #pragma unroll
    for (int off = 32; off; off >>= 1) vs += __shfl_xor(vs, off, 64);
    const float rstd = rsqrtf(vs * (1.0f / EMBED) + LN_EPS);

    short8 gv  = *reinterpret_cast<const short8*>(g + co);
    short8 btv = *reinterpret_cast<const short8*>(bt + co);
    if (OUT32 && *dflag) {
        float4 o0, o1;
        float of[8];
        #pragma unroll
        for (int j = 0; j < 8; ++j)
            of[j] = x[j] * rstd * bf2f(((const __hip_bfloat16*)&gv)[j]) + bf2f(((const __hip_bfloat16*)&btv)[j]);
        o0 = make_float4(of[0], of[1], of[2], of[3]);
        o1 = make_float4(of[4], of[5], of[6], of[7]);
        *reinterpret_cast<float4*>((float*)out + base) = o0;
        *reinterpret_cast<float4*>((float*)out + base + 4) = o1;
    } else {
        alignas(16) __hip_bfloat16 o[8];
        #pragma unroll
        for (int j = 0; j < 8; ++j)
            o[j] = f2bf(x[j] * rstd * bf2f(((const __hip_bfloat16*)&gv)[j]) + bf2f(((const __hip_bfloat16*)&btv)[j]));
        *reinterpret_cast<uint4*>((__hip_bfloat16*)out + base) = *reinterpret_cast<const uint4*>(o);
    }
}

// ---------------- launch ----------------
extern "C" void kernel_launch(void* const* d_in, const int* in_sizes, int n_in,
                              void* d_out, int out_size, void* d_ws, size_t ws_size,
                              hipStream_t stream)
{
    (void)in_sizes; (void)n_in; (void)out_size; (void)ws_size;

    const void* query = d_in[0];
    const void* keyi  = d_in[1];
    const void* vali  = d_in[2];
    const void* Wq = d_in[3];  const void* bq = d_in[4];
    const void* Wk = d_in[5];  const void* bk = d_in[6];
    const void* Wv = d_in[7];  const void* bv = d_in[8];
    const void* Wo = d_in[9];  const void* bo = d_in[10];
    const void* g1 = d_in[11]; const void* be1 = d_in[12];
    const void* g2 = d_in[13]; const void* be2 = d_in[14];
    const void* W1 = d_in[15]; const void* b1 = d_in[16];
    const void* W2 = d_in[17]; const void* b2 = d_in[18];

    // ws: 64B flag | 16KB biasb | 6MB Wcat | 8 x 8MB units (~70MB, proven)
    int* dflag = (int*)d_ws;
    __hip_bfloat16* biasb = (__hip_bfloat16*)((char*)d_ws + 64);
    __hip_bfloat16* Wcat = biasb + 8192;
    __hip_bfloat16* buf = Wcat + 4 * 512 * 512 + 2 * 512 * 2048;
    __hip_bfloat16* bqkvb = biasb;
    __hip_bfloat16* bob  = biasb + 1536;
    __hip_bfloat16* b1b  = biasb + 2048;
    __hip_bfloat16* b2b  = biasb + 4096;
    __hip_bfloat16* g1b  = biasb + 4608;
    __hip_bfloat16* be1b = biasb + 5120;
    __hip_bfloat16* g2b  = biasb + 5632;
    __hip_bfloat16* be2b = biasb + 6144;
    // units
    __hip_bfloat16* qkvbf  = buf;                  // 0..2 (qbf live till LN1; kbf/vbf read during QKV)
    __hip_bfloat16* QKVo   = buf + 3 * NB;         // 3..5 (Q at 3, K at 4; V slot 5 unused)
    __hip_bfloat16* Qb = QKVo;
    __hip_bfloat16* Kb = QKVo + NB;
    __hip_bfloat16* Vt     = buf + 6 * NB;         // unit 6: free during QKV (no alias with inputs)
    __hip_bfloat16* ctx    = buf + 2 * NB;         // vbf dead after QKV
    __hip_bfloat16* Yw     = buf + 4 * NB;         // Wo partials: units 4,5
    __hip_bfloat16* x1     = buf + 3 * NB;         // Qb dead after attn
    __hip_bfloat16* hbf    = buf + 4 * NB;         // FFN1 out: units 4..7 (Vt dead after attn)
    __hip_bfloat16* Yf     = buf + 1 * NB;         // FFN2 partials: units 1,2

    prep_kernel<<<6913, 256, 0, stream>>>(
        query, keyi, vali, Wq, Wk, Wv, Wo, W1, W2,
        bq, bk, bv, bo, b1, b2, g1, be1, g2, be2,
        qkvbf, Wcat, biasb, dflag);

    gemm_qkv_fused_kernel<<<dim3(192, 4), 256, 0, stream>>>(qkvbf, Wcat, bqkvb, QKVo, Vt);

    attn_mfma_kernel<<<dim3(SS / 128, BB * NHEAD), 256, 0, stream>>>(
        Qb, Kb, Vt, ctx);

    // Wo projection split-K2 (partials, bias folded into LN1)
    gemm_bt_lds_kernel<0, 0><<<dim3(MROWS / 128, EMBED / 128, 2), 256, 0, stream>>>(
        ctx, Wcat + 3 * 512 * 512, nullptr, Yw, MROWS, EMBED, EMBED, EMBED / 2);
    add_ln_split_kernel<0><<<MROWS / 4, 256, 0, stream>>>(
        qkvbf, Yw, Yw + NB, bob, g1b, be1b, x1, dflag);

    // FFN
    gemm_bt_lds_kernel<1, 1><<<dim3(MROWS / 128, FFN / 128), 256, 0, stream>>>(
        x1, Wcat + 4 * 512 * 512, b1b, hbf, MROWS, FFN, EMBED, 0);
    gemm_bt_lds_kernel<0, 0><<<dim3(MROWS / 128, EMBED / 128, 2), 256, 0, stream>>>(
        hbf, Wcat + 4 * 512 * 512 + 512 * 2048, nullptr, Yf, MROWS, EMBED, FFN, FFN / 2);
    add_ln_split_kernel<1><<<MROWS / 4, 256, 0, stream>>>(
        x1, Yf, Yf + NB, b2b, g2b, be2b, d_out, dflag);
}